// Round 7
// baseline (392.948 us; speedup 1.0000x reference)
//
#include <hip/hip_runtime.h>
#include <math.h>

#define NUM_CODES 1024
#define DIM 64
#define HW 1024
#define NPTS 65536
#define CAP 8
#define W_WINDOW 1.5e-3f   // hh-only window; validated rounds 5-6 (absmax 0)

using short8 = __attribute__((ext_vector_type(8))) short;
using f32x4  = __attribute__((ext_vector_type(4))) float;

// ---- numpy-exact helpers (verified rounds 2-6: absmax 0.0) ----
__device__ __forceinline__ float pairwise_sumsq64(const float* v) {
    float r[8];
#pragma unroll
    for (int j = 0; j < 8; ++j) r[j] = __fmul_rn(v[j], v[j]);
#pragma unroll
    for (int i = 8; i < 64; i += 8) {
#pragma unroll
        for (int j = 0; j < 8; ++j)
            r[j] = __fadd_rn(r[j], __fmul_rn(v[i + j], v[i + j]));
    }
    return __fadd_rn(
        __fadd_rn(__fadd_rn(r[0], r[1]), __fadd_rn(r[2], r[3])),
        __fadd_rn(__fadd_rn(r[4], r[5]), __fadd_rn(r[6], r[7])));
}

__device__ __forceinline__ float replica_d(const float* x, const float* wr,
                                           float t1, float t3k) {
    float acc = 0.0f;
#pragma unroll
    for (int j = 0; j < 64; ++j) acc = __fmaf_rn(x[j], wr[j], acc);
    return __fadd_rn(__fsub_rn(t1, __fmul_rn(2.0f, acc)), t3k);
}

__device__ __forceinline__ unsigned short bf16_rne(float v) {
    unsigned int u = __float_as_uint(v);
    return (unsigned short)((u + 0x7fffu + ((u >> 16) & 1u)) >> 16);
}

// ---- Kernel 0: prep  w_hi (bf16) + t3 (numpy-exact) ----
__global__ void vq_prep_kernel(const float* __restrict__ w,
                               unsigned short* __restrict__ whi,
                               float* __restrict__ t3) {
    int k = blockIdx.x * blockDim.x + threadIdx.x;
    if (k >= NUM_CODES) return;
    float row[64];
#pragma unroll
    for (int j = 0; j < 64; ++j) row[j] = w[k * DIM + j];
    t3[k] = pairwise_sumsq64(row);
#pragma unroll
    for (int j = 0; j < 64; ++j) whi[k * DIM + j] = bf16_rne(row[j]);
}

// ---- Kernel 1: main. Block = 256 thr = 4 waves; 64 points (r4 skeleton).
// Code-split: wave wv handles ALL 4 point-tiles x codes [wv*256, wv*256+256).
__global__ __launch_bounds__(256, 4) void vq_main_kernel(
        const float* __restrict__ z,
        const float* __restrict__ w,
        const unsigned short* __restrict__ whi,
        const float* __restrict__ t3,
        float* __restrict__ out) {
    __shared__ __align__(16) unsigned short s_xhi[64 * 72];
    __shared__ float s_pmin[4][64];
    __shared__ float s_thr[64];
    __shared__ int s_list[64 * CAP];
    __shared__ int s_cnt[64];
    __shared__ int s_best[64];

    const int tid = threadIdx.x;
    const int lane = tid & 63;
    const int wv = tid >> 6;          // 0..3
    const int n0 = blockIdx.x * 64;
    const int b = n0 >> 10;
    const int hw0 = n0 & (HW - 1);

    if (tid < 64) s_cnt[tid] = 0;

    // stage 64 points as bf16-hi into LDS; coalesced 64-wide global reads
    {
        int hw_off = tid & 63;
        int dbase = tid >> 6;         // 0..3
#pragma unroll
        for (int i = 0; i < 16; ++i) {
            int d = dbase + i * 4;
            float v = z[((size_t)(b * 64 + d)) * HW + hw0 + hw_off];
            s_xhi[hw_off * 72 + d] = bf16_rne(v);
        }
    }
    __syncthreads();

    const int col = lane & 15;
    const int q = lane >> 4;

    // A fragments for all 4 point-tiles (hi only; layout verified r3-r6)
    short8 ah0[4], ah1[4];
#pragma unroll
    for (int at = 0; at < 4; ++at) {
        int arow = at * 16 + col;
        ah0[at] = *(const short8*)&s_xhi[arow * 72 + q * 8];
        ah1[at] = *(const short8*)&s_xhi[arow * 72 + 32 + q * 8];
    }

    const int T0 = wv * 16;

    // ---- pass 1: per-point min over this wave's 256 codes ----
    float s1[4][4];
#pragma unroll
    for (int at = 0; at < 4; ++at)
#pragma unroll
        for (int r = 0; r < 4; ++r) s1[at][r] = INFINITY;

#pragma unroll 4
    for (int t = 0; t < 16; ++t) {
        int code = (T0 + t) * 16 + col;
        short8 b0 = *(const short8*)(whi + code * 64 + q * 8);
        short8 b1 = *(const short8*)(whi + code * 64 + 32 + q * 8);
        float t3v = t3[code];
#pragma unroll
        for (int at = 0; at < 4; ++at) {
            f32x4 c = {0.f, 0.f, 0.f, 0.f};
            c = __builtin_amdgcn_mfma_f32_16x16x32_bf16(ah0[at], b0, c, 0, 0, 0);
            c = __builtin_amdgcn_mfma_f32_16x16x32_bf16(ah1[at], b1, c, 0, 0, 0);
#pragma unroll
            for (int r = 0; r < 4; ++r)
                s1[at][r] = fminf(s1[at][r], fmaf(-2.0f, c[r], t3v));
        }
    }

    // reduce over the 16 lanes (col bits) sharing each point
#pragma unroll
    for (int mask = 1; mask <= 8; mask <<= 1)
#pragma unroll
        for (int at = 0; at < 4; ++at)
#pragma unroll
            for (int r = 0; r < 4; ++r)
                s1[at][r] = fminf(s1[at][r], __shfl_xor(s1[at][r], mask, 64));

    if (col == 0) {
#pragma unroll
        for (int at = 0; at < 4; ++at)
#pragma unroll
            for (int r = 0; r < 4; ++r)
                s_pmin[wv][at * 16 + q * 4 + r] = s1[at][r];
    }
    __syncthreads();

    if (tid < 64) {
        float m = fminf(fminf(s_pmin[0][tid], s_pmin[1][tid]),
                        fminf(s_pmin[2][tid], s_pmin[3][tid]));
        s_thr[tid] = m + W_WINDOW;
    }
    __syncthreads();

    float thr[4][4];
#pragma unroll
    for (int at = 0; at < 4; ++at)
#pragma unroll
        for (int r = 0; r < 4; ++r)
            thr[at][r] = s_thr[at * 16 + q * 4 + r];

    // ---- pass 2: recompute scores (bitwise-identical), collect candidates ----
#pragma unroll 4
    for (int t = 0; t < 16; ++t) {
        int code = (T0 + t) * 16 + col;
        short8 b0 = *(const short8*)(whi + code * 64 + q * 8);
        short8 b1 = *(const short8*)(whi + code * 64 + 32 + q * 8);
        float t3v = t3[code];
#pragma unroll
        for (int at = 0; at < 4; ++at) {
            f32x4 c = {0.f, 0.f, 0.f, 0.f};
            c = __builtin_amdgcn_mfma_f32_16x16x32_bf16(ah0[at], b0, c, 0, 0, 0);
            c = __builtin_amdgcn_mfma_f32_16x16x32_bf16(ah1[at], b1, c, 0, 0, 0);
#pragma unroll
            for (int r = 0; r < 4; ++r) {
                float s = fmaf(-2.0f, c[r], t3v);
                if (s <= thr[at][r]) {
                    int pt = at * 16 + q * 4 + r;
                    int idx = atomicAdd(&s_cnt[pt], 1);
                    if (idx < CAP) s_list[pt * CAP + idx] = code;
                }
            }
        }
    }
    __syncthreads();

    // ---- selection: exact fp32 replica among candidates (x from L2-hot z) ----
    if (tid < 64) {
        int pt = tid;
        int m = s_cnt[pt];
        int best = s_list[pt * CAP];
        if (m > 1) {
            float x[64];
#pragma unroll
            for (int j = 0; j < 64; ++j)
                x[j] = z[((size_t)(b * 64 + j)) * HW + hw0 + pt];
            float t1 = pairwise_sumsq64(x);
            float dbest = INFINITY;
            if (m <= CAP) {
                int ks[CAP];
                for (int i = 0; i < m; ++i) ks[i] = s_list[pt * CAP + i];
                for (int i = 1; i < m; ++i) {          // sort ascending k
                    int key = ks[i]; int j2 = i - 1;
                    while (j2 >= 0 && ks[j2] > key) { ks[j2 + 1] = ks[j2]; --j2; }
                    ks[j2 + 1] = key;
                }
                for (int i = 0; i < m; ++i) {          // first-occurrence argmin
                    int k = ks[i];
                    float d = replica_d(x, w + (size_t)k * DIM, t1, t3[k]);
                    if (d < dbest) { dbest = d; best = k; }
                }
            } else {
                best = 0;                               // overflow guard: full scan
                for (int k = 0; k < NUM_CODES; ++k) {
                    float d = replica_d(x, w + (size_t)k * DIM, t1, t3[k]);
                    if (d < dbest) { dbest = d; best = k; }
                }
            }
        }
        s_best[pt] = best;
    }
    __syncthreads();

    // ---- output: out[b, c, hw0+pt] = w[best[pt]][c], coalesced 64-wide ----
    {
        int pt = tid & 63;
        int cb = tid >> 6;            // 0..3
        int bk = s_best[pt];
        const float* wrow = w + (size_t)bk * DIM;
#pragma unroll
        for (int i = 0; i < 16; ++i) {
            int c = cb + i * 4;
            out[((size_t)(b * 64 + c)) * HW + hw0 + pt] = wrow[c];
        }
    }
}

extern "C" void kernel_launch(void* const* d_in, const int* in_sizes, int n_in,
                              void* d_out, int out_size, void* d_ws, size_t ws_size,
                              hipStream_t stream) {
    const float* z = (const float*)d_in[0];
    const float* w = (const float*)d_in[1];
    float* out = (float*)d_out;

    unsigned short* whi = (unsigned short*)d_ws;        // 128 KB
    float* t3 = (float*)((char*)d_ws + 131072);         // 4 KB

    vq_prep_kernel<<<NUM_CODES / 256, 256, 0, stream>>>(w, whi, t3);
    vq_main_kernel<<<NPTS / 64, 256, 0, stream>>>(z, w, whi, t3, out);
}

// Round 8
// 390.477 us; speedup vs baseline: 1.0063x; 1.0063x over previous
//
#include <hip/hip_runtime.h>
#include <math.h>

#define NUM_CODES 1024
#define DIM 64
#define HW 1024
#define NPTS 65536
#define CAP 8
#define W_WINDOW 1.5e-3f   // hh-only window; validated rounds 5-7 (absmax 0)

using short8 = __attribute__((ext_vector_type(8))) short;
using f32x4  = __attribute__((ext_vector_type(4))) float;

// ---- numpy-exact helpers (verified rounds 2-7: absmax 0.0) ----
__device__ __forceinline__ float pairwise_sumsq64(const float* v) {
    float r[8];
#pragma unroll
    for (int j = 0; j < 8; ++j) r[j] = __fmul_rn(v[j], v[j]);
#pragma unroll
    for (int i = 8; i < 64; i += 8) {
#pragma unroll
        for (int j = 0; j < 8; ++j)
            r[j] = __fadd_rn(r[j], __fmul_rn(v[i + j], v[i + j]));
    }
    return __fadd_rn(
        __fadd_rn(__fadd_rn(r[0], r[1]), __fadd_rn(r[2], r[3])),
        __fadd_rn(__fadd_rn(r[4], r[5]), __fadd_rn(r[6], r[7])));
}

__device__ __forceinline__ float replica_d(const float* x, const float* wr,
                                           float t1, float t3k) {
    float acc = 0.0f;
#pragma unroll
    for (int j = 0; j < 64; ++j) acc = __fmaf_rn(x[j], wr[j], acc);
    return __fadd_rn(__fsub_rn(t1, __fmul_rn(2.0f, acc)), t3k);
}

__device__ __forceinline__ unsigned short bf16_rne(float v) {
    unsigned int u = __float_as_uint(v);
    return (unsigned short)((u + 0x7fffu + ((u >> 16) & 1u)) >> 16);
}

// ---- Kernel 0: prep  w_hi (bf16) + t3 (numpy-exact) ----
__global__ void vq_prep_kernel(const float* __restrict__ w,
                               unsigned short* __restrict__ whi,
                               float* __restrict__ t3) {
    int k = blockIdx.x * blockDim.x + threadIdx.x;
    if (k >= NUM_CODES) return;
    float row[64];
#pragma unroll
    for (int j = 0; j < 64; ++j) row[j] = w[k * DIM + j];
    t3[k] = pairwise_sumsq64(row);
#pragma unroll
    for (int j = 0; j < 64; ++j) whi[k * DIM + j] = bf16_rne(row[j]);
}

// ---- Kernel 1: main. Block = 256 thr = 4 waves; 64 points (r4 skeleton).
// Code-split: wave wv handles ALL 4 point-tiles x codes [wv*256, wv*256+256).
// launch_bounds (256,2): VGPR cap 128 (cap = 256/arg on this toolchain;
// (256,4) caps at 64 and SPILLS -- measured r7: 393us, 41MB scratch writes).
__global__ __launch_bounds__(256, 2) void vq_main_kernel(
        const float* __restrict__ z,
        const float* __restrict__ w,
        const unsigned short* __restrict__ whi,
        const float* __restrict__ t3,
        float* __restrict__ out) {
    __shared__ __align__(16) unsigned short s_xhi[64 * 72];
    __shared__ float s_pmin[4][64];
    __shared__ float s_thr[64];
    __shared__ int s_list[64 * CAP];
    __shared__ int s_cnt[64];
    __shared__ int s_best[64];

    const int tid = threadIdx.x;
    const int lane = tid & 63;
    const int wv = tid >> 6;          // 0..3
    const int n0 = blockIdx.x * 64;
    const int b = n0 >> 10;
    const int hw0 = n0 & (HW - 1);

    if (tid < 64) s_cnt[tid] = 0;

    // stage 64 points as bf16-hi into LDS; coalesced 64-wide global reads
    {
        int hw_off = tid & 63;
        int dbase = tid >> 6;         // 0..3
#pragma unroll
        for (int i = 0; i < 16; ++i) {
            int d = dbase + i * 4;
            float v = z[((size_t)(b * 64 + d)) * HW + hw0 + hw_off];
            s_xhi[hw_off * 72 + d] = bf16_rne(v);
        }
    }
    __syncthreads();

    const int col = lane & 15;
    const int q = lane >> 4;

    // A fragments for all 4 point-tiles (hi only; layout verified r3-r7)
    short8 ah0[4], ah1[4];
#pragma unroll
    for (int at = 0; at < 4; ++at) {
        int arow = at * 16 + col;
        ah0[at] = *(const short8*)&s_xhi[arow * 72 + q * 8];
        ah1[at] = *(const short8*)&s_xhi[arow * 72 + 32 + q * 8];
    }

    const int T0 = wv * 16;

    // ---- pass 1: per-point min over this wave's 256 codes ----
    float s1[4][4];
#pragma unroll
    for (int at = 0; at < 4; ++at)
#pragma unroll
        for (int r = 0; r < 4; ++r) s1[at][r] = INFINITY;

#pragma unroll 4
    for (int t = 0; t < 16; ++t) {
        int code = (T0 + t) * 16 + col;
        short8 b0 = *(const short8*)(whi + code * 64 + q * 8);
        short8 b1 = *(const short8*)(whi + code * 64 + 32 + q * 8);
        float t3v = t3[code];
#pragma unroll
        for (int at = 0; at < 4; ++at) {
            f32x4 c = {0.f, 0.f, 0.f, 0.f};
            c = __builtin_amdgcn_mfma_f32_16x16x32_bf16(ah0[at], b0, c, 0, 0, 0);
            c = __builtin_amdgcn_mfma_f32_16x16x32_bf16(ah1[at], b1, c, 0, 0, 0);
#pragma unroll
            for (int r = 0; r < 4; ++r)
                s1[at][r] = fminf(s1[at][r], fmaf(-2.0f, c[r], t3v));
        }
    }

    // reduce over the 16 lanes (col bits) sharing each point
#pragma unroll
    for (int mask = 1; mask <= 8; mask <<= 1)
#pragma unroll
        for (int at = 0; at < 4; ++at)
#pragma unroll
            for (int r = 0; r < 4; ++r)
                s1[at][r] = fminf(s1[at][r], __shfl_xor(s1[at][r], mask, 64));

    if (col == 0) {
#pragma unroll
        for (int at = 0; at < 4; ++at)
#pragma unroll
            for (int r = 0; r < 4; ++r)
                s_pmin[wv][at * 16 + q * 4 + r] = s1[at][r];
    }
    __syncthreads();

    if (tid < 64) {
        float m = fminf(fminf(s_pmin[0][tid], s_pmin[1][tid]),
                        fminf(s_pmin[2][tid], s_pmin[3][tid]));
        s_thr[tid] = m + W_WINDOW;
    }
    __syncthreads();

    float thr[4][4];
#pragma unroll
    for (int at = 0; at < 4; ++at)
#pragma unroll
        for (int r = 0; r < 4; ++r)
            thr[at][r] = s_thr[at * 16 + q * 4 + r];

    // ---- pass 2: recompute scores (bitwise-identical), collect candidates ----
#pragma unroll 4
    for (int t = 0; t < 16; ++t) {
        int code = (T0 + t) * 16 + col;
        short8 b0 = *(const short8*)(whi + code * 64 + q * 8);
        short8 b1 = *(const short8*)(whi + code * 64 + 32 + q * 8);
        float t3v = t3[code];
#pragma unroll
        for (int at = 0; at < 4; ++at) {
            f32x4 c = {0.f, 0.f, 0.f, 0.f};
            c = __builtin_amdgcn_mfma_f32_16x16x32_bf16(ah0[at], b0, c, 0, 0, 0);
            c = __builtin_amdgcn_mfma_f32_16x16x32_bf16(ah1[at], b1, c, 0, 0, 0);
#pragma unroll
            for (int r = 0; r < 4; ++r) {
                float s = fmaf(-2.0f, c[r], t3v);
                if (s <= thr[at][r]) {
                    int pt = at * 16 + q * 4 + r;
                    int idx = atomicAdd(&s_cnt[pt], 1);
                    if (idx < CAP) s_list[pt * CAP + idx] = code;
                }
            }
        }
    }
    __syncthreads();

    // ---- selection: exact fp32 replica among candidates (x from L2-hot z) ----
    if (tid < 64) {
        int pt = tid;
        int m = s_cnt[pt];
        int best = s_list[pt * CAP];
        if (m > 1) {
            float x[64];
#pragma unroll
            for (int j = 0; j < 64; ++j)
                x[j] = z[((size_t)(b * 64 + j)) * HW + hw0 + pt];
            float t1 = pairwise_sumsq64(x);
            float dbest = INFINITY;
            if (m <= CAP) {
                int ks[CAP];
                for (int i = 0; i < m; ++i) ks[i] = s_list[pt * CAP + i];
                for (int i = 1; i < m; ++i) {          // sort ascending k
                    int key = ks[i]; int j2 = i - 1;
                    while (j2 >= 0 && ks[j2] > key) { ks[j2 + 1] = ks[j2]; --j2; }
                    ks[j2 + 1] = key;
                }
                for (int i = 0; i < m; ++i) {          // first-occurrence argmin
                    int k = ks[i];
                    float d = replica_d(x, w + (size_t)k * DIM, t1, t3[k]);
                    if (d < dbest) { dbest = d; best = k; }
                }
            } else {
                best = 0;                               // overflow guard: full scan
                for (int k = 0; k < NUM_CODES; ++k) {
                    float d = replica_d(x, w + (size_t)k * DIM, t1, t3[k]);
                    if (d < dbest) { dbest = d; best = k; }
                }
            }
        }
        s_best[pt] = best;
    }
    __syncthreads();

    // ---- output: out[b, c, hw0+pt] = w[best[pt]][c], coalesced 64-wide ----
    {
        int pt = tid & 63;
        int cb = tid >> 6;            // 0..3
        int bk = s_best[pt];
        const float* wrow = w + (size_t)bk * DIM;
#pragma unroll
        for (int i = 0; i < 16; ++i) {
            int c = cb + i * 4;
            out[((size_t)(b * 64 + c)) * HW + hw0 + pt] = wrow[c];
        }
    }
}

extern "C" void kernel_launch(void* const* d_in, const int* in_sizes, int n_in,
                              void* d_out, int out_size, void* d_ws, size_t ws_size,
                              hipStream_t stream) {
    const float* z = (const float*)d_in[0];
    const float* w = (const float*)d_in[1];
    float* out = (float*)d_out;

    unsigned short* whi = (unsigned short*)d_ws;        // 128 KB
    float* t3 = (float*)((char*)d_ws + 131072);         // 4 KB

    vq_prep_kernel<<<NUM_CODES / 256, 256, 0, stream>>>(w, whi, t3);
    vq_main_kernel<<<NPTS / 64, 256, 0, stream>>>(z, w, whi, t3, out);
}

// Round 9
// 93.186 us; speedup vs baseline: 4.2168x; 4.1903x over previous
//
#include <hip/hip_runtime.h>
#include <math.h>

#define NUM_CODES 1024
#define DIM 64
#define HW 1024
#define NPTS 65536
#define CAP 8
#define W_WINDOW 1.2e-4f

using short8 = __attribute__((ext_vector_type(8))) short;
using f32x4  = __attribute__((ext_vector_type(4))) float;

// ---- numpy-exact helpers (verified round 2/3: absmax 0.0) ----
__device__ __forceinline__ float pairwise_sumsq64(const float* v) {
    float r[8];
#pragma unroll
    for (int j = 0; j < 8; ++j) r[j] = __fmul_rn(v[j], v[j]);
#pragma unroll
    for (int i = 8; i < 64; i += 8) {
#pragma unroll
        for (int j = 0; j < 8; ++j)
            r[j] = __fadd_rn(r[j], __fmul_rn(v[i + j], v[i + j]));
    }
    return __fadd_rn(
        __fadd_rn(__fadd_rn(r[0], r[1]), __fadd_rn(r[2], r[3])),
        __fadd_rn(__fadd_rn(r[4], r[5]), __fadd_rn(r[6], r[7])));
}

__device__ __forceinline__ float replica_d(const float* x, const float* wr,
                                           float t1, float t3k) {
    float acc = 0.0f;
#pragma unroll
    for (int j = 0; j < 64; ++j) acc = __fmaf_rn(x[j], wr[j], acc);
    return __fadd_rn(__fsub_rn(t1, __fmul_rn(2.0f, acc)), t3k);
}

__device__ __forceinline__ unsigned short bf16_rne(float v) {
    unsigned int u = __float_as_uint(v);
    return (unsigned short)((u + 0x7fffu + ((u >> 16) & 1u)) >> 16);
}

// ---- Kernel 0: prep  w_hi/w_lo (bf16 split) + t3 (numpy-exact) ----
__global__ void vq_prep_kernel(const float* __restrict__ w,
                               unsigned short* __restrict__ whi,
                               unsigned short* __restrict__ wlo,
                               float* __restrict__ t3) {
    int k = blockIdx.x * blockDim.x + threadIdx.x;
    if (k >= NUM_CODES) return;
    float row[64];
#pragma unroll
    for (int j = 0; j < 64; ++j) row[j] = w[k * DIM + j];
    t3[k] = pairwise_sumsq64(row);
#pragma unroll
    for (int j = 0; j < 64; ++j) {
        unsigned short h = bf16_rne(row[j]);
        float hf = __uint_as_float(((unsigned int)h) << 16);
        float lo = row[j] - hf;                 // exact
        whi[k * DIM + j] = h;
        wlo[k * DIM + j] = bf16_rne(lo);
    }
}

// ---- Kernel 1: main. Block = 256 thr = 4 waves; 64 points.
// Code-split: wave wv handles ALL 4 point-tiles x codes [wv*256, wv*256+256).
__global__ __launch_bounds__(256, 2) void vq_main_kernel(
        const float* __restrict__ z,
        const float* __restrict__ w,
        const unsigned short* __restrict__ whi,
        const unsigned short* __restrict__ wlo,
        const float* __restrict__ t3,
        float* __restrict__ out) {
    __shared__ __align__(16) unsigned short s_xhi[64 * 72];
    __shared__ __align__(16) unsigned short s_xlo[64 * 72];
    __shared__ float s_xf[64 * 66];
    __shared__ float s_pmin[4][64];
    __shared__ float s_thr[64];
    __shared__ int s_list[64 * CAP];
    __shared__ int s_cnt[64];
    __shared__ int s_best[64];

    const int tid = threadIdx.x;
    const int lane = tid & 63;
    const int wv = tid >> 6;
    const int n0 = blockIdx.x * 64;
    const int b = n0 >> 10;
    const int hw0 = n0 & (HW - 1);

    if (tid < 64) s_cnt[tid] = 0;

    // stage 64 points (f32 + bf16 hi/lo) into LDS; coalesced global reads
    {
        int hw_off = tid & 63;
        int dbase = tid >> 6;
#pragma unroll
        for (int i = 0; i < 16; ++i) {
            int d = dbase + i * 4;
            float v = z[((size_t)(b * 64 + d)) * HW + hw0 + hw_off];
            unsigned short h = bf16_rne(v);
            float hf = __uint_as_float(((unsigned int)h) << 16);
            s_xhi[hw_off * 72 + d] = h;
            s_xlo[hw_off * 72 + d] = bf16_rne(v - hf);
            s_xf[hw_off * 66 + d] = v;
        }
    }
    __syncthreads();

    const int col = lane & 15;
    const int q = lane >> 4;

    // A fragments for all 4 point-tiles (layout verified round 3)
    short8 ah0[4], ah1[4], al0[4], al1[4];
#pragma unroll
    for (int at = 0; at < 4; ++at) {
        int arow = at * 16 + col;
        ah0[at] = *(const short8*)&s_xhi[arow * 72 + q * 8];
        ah1[at] = *(const short8*)&s_xhi[arow * 72 + 32 + q * 8];
        al0[at] = *(const short8*)&s_xlo[arow * 72 + q * 8];
        al1[at] = *(const short8*)&s_xlo[arow * 72 + 32 + q * 8];
    }

    const int T0 = wv * 16;

    // ---- pass 1: per-point min over this wave's 256 codes ----
    float s1[4][4];
#pragma unroll
    for (int at = 0; at < 4; ++at)
#pragma unroll
        for (int r = 0; r < 4; ++r) s1[at][r] = INFINITY;

#pragma unroll 4
    for (int t = 0; t < 16; ++t) {
        int code = (T0 + t) * 16 + col;
        short8 b0 = *(const short8*)(whi + code * 64 + q * 8);
        short8 b1 = *(const short8*)(whi + code * 64 + 32 + q * 8);
        short8 b2 = *(const short8*)(wlo + code * 64 + q * 8);
        short8 b3 = *(const short8*)(wlo + code * 64 + 32 + q * 8);
        float t3v = t3[code];
#pragma unroll
        for (int at = 0; at < 4; ++at) {
            f32x4 c = {0.f, 0.f, 0.f, 0.f};
            c = __builtin_amdgcn_mfma_f32_16x16x32_bf16(ah0[at], b0, c, 0, 0, 0);
            c = __builtin_amdgcn_mfma_f32_16x16x32_bf16(ah1[at], b1, c, 0, 0, 0);
            c = __builtin_amdgcn_mfma_f32_16x16x32_bf16(al0[at], b0, c, 0, 0, 0);
            c = __builtin_amdgcn_mfma_f32_16x16x32_bf16(al1[at], b1, c, 0, 0, 0);
            c = __builtin_amdgcn_mfma_f32_16x16x32_bf16(ah0[at], b2, c, 0, 0, 0);
            c = __builtin_amdgcn_mfma_f32_16x16x32_bf16(ah1[at], b3, c, 0, 0, 0);
#pragma unroll
            for (int r = 0; r < 4; ++r)
                s1[at][r] = fminf(s1[at][r], fmaf(-2.0f, c[r], t3v));
        }
    }

    // reduce over the 16 lanes (col bits) sharing each point
#pragma unroll
    for (int mask = 1; mask <= 8; mask <<= 1)
#pragma unroll
        for (int at = 0; at < 4; ++at)
#pragma unroll
            for (int r = 0; r < 4; ++r)
                s1[at][r] = fminf(s1[at][r], __shfl_xor(s1[at][r], mask, 64));

    if (col == 0) {
#pragma unroll
        for (int at = 0; at < 4; ++at)
#pragma unroll
            for (int r = 0; r < 4; ++r)
                s_pmin[wv][at * 16 + q * 4 + r] = s1[at][r];
    }
    __syncthreads();

    if (tid < 64) {
        float m = fminf(fminf(s_pmin[0][tid], s_pmin[1][tid]),
                        fminf(s_pmin[2][tid], s_pmin[3][tid]));
        s_thr[tid] = m + W_WINDOW;
    }
    __syncthreads();

    float thr[4][4];
#pragma unroll
    for (int at = 0; at < 4; ++at)
#pragma unroll
        for (int r = 0; r < 4; ++r)
            thr[at][r] = s_thr[at * 16 + q * 4 + r];

    // ---- pass 2: recompute scores, collect candidates within window ----
#pragma unroll 4
    for (int t = 0; t < 16; ++t) {
        int code = (T0 + t) * 16 + col;
        short8 b0 = *(const short8*)(whi + code * 64 + q * 8);
        short8 b1 = *(const short8*)(whi + code * 64 + 32 + q * 8);
        short8 b2 = *(const short8*)(wlo + code * 64 + q * 8);
        short8 b3 = *(const short8*)(wlo + code * 64 + 32 + q * 8);
        float t3v = t3[code];
#pragma unroll
        for (int at = 0; at < 4; ++at) {
            f32x4 c = {0.f, 0.f, 0.f, 0.f};
            c = __builtin_amdgcn_mfma_f32_16x16x32_bf16(ah0[at], b0, c, 0, 0, 0);
            c = __builtin_amdgcn_mfma_f32_16x16x32_bf16(ah1[at], b1, c, 0, 0, 0);
            c = __builtin_amdgcn_mfma_f32_16x16x32_bf16(al0[at], b0, c, 0, 0, 0);
            c = __builtin_amdgcn_mfma_f32_16x16x32_bf16(al1[at], b1, c, 0, 0, 0);
            c = __builtin_amdgcn_mfma_f32_16x16x32_bf16(ah0[at], b2, c, 0, 0, 0);
            c = __builtin_amdgcn_mfma_f32_16x16x32_bf16(ah1[at], b3, c, 0, 0, 0);
#pragma unroll
            for (int r = 0; r < 4; ++r) {
                float s = fmaf(-2.0f, c[r], t3v);
                if (s <= thr[at][r]) {
                    int pt = at * 16 + q * 4 + r;
                    int idx = atomicAdd(&s_cnt[pt], 1);
                    if (idx < CAP) s_list[pt * CAP + idx] = code;
                }
            }
        }
    }
    __syncthreads();

    // ---- selection: exact fp32 replica among candidates ----
    if (tid < 64) {
        int pt = tid;
        int m = s_cnt[pt];
        const float* xrow = &s_xf[pt * 66];
        int best = s_list[pt * CAP];
        if (m > 1) {
            float t1 = pairwise_sumsq64(xrow);
            float dbest = INFINITY;
            if (m <= CAP) {
                int ks[CAP];
                for (int i = 0; i < m; ++i) ks[i] = s_list[pt * CAP + i];
                for (int i = 1; i < m; ++i) {
                    int key = ks[i]; int j2 = i - 1;
                    while (j2 >= 0 && ks[j2] > key) { ks[j2 + 1] = ks[j2]; --j2; }
                    ks[j2 + 1] = key;
                }
                for (int i = 0; i < m; ++i) {
                    int k = ks[i];
                    float d = replica_d(xrow, w + (size_t)k * DIM, t1, t3[k]);
                    if (d < dbest) { dbest = d; best = k; }
                }
            } else {
                best = 0;
                for (int k = 0; k < NUM_CODES; ++k) {
                    float d = replica_d(xrow, w + (size_t)k * DIM, t1, t3[k]);
                    if (d < dbest) { dbest = d; best = k; }
                }
            }
        }
        s_best[pt] = best;
    }
    __syncthreads();

    // ---- output: out[b, c, hw0+pt] = w[best[pt]][c], coalesced stores ----
    {
        int pt = tid & 63;
        int cb = tid >> 6;
        int bk = s_best[pt];
        const float* wrow = w + (size_t)bk * DIM;
#pragma unroll
        for (int i = 0; i < 16; ++i) {
            int c = cb + i * 4;
            out[((size_t)(b * 64 + c)) * HW + hw0 + pt] = wrow[c];
        }
    }
}

extern "C" void kernel_launch(void* const* d_in, const int* in_sizes, int n_in,
                              void* d_out, int out_size, void* d_ws, size_t ws_size,
                              hipStream_t stream) {
    const float* z = (const float*)d_in[0];
    const float* w = (const float*)d_in[1];
    float* out = (float*)d_out;

    unsigned short* whi = (unsigned short*)d_ws;                    // 128 KB
    unsigned short* wlo = (unsigned short*)((char*)d_ws + 131072);  // 128 KB
    float* t3 = (float*)((char*)d_ws + 262144);                     // 4 KB

    vq_prep_kernel<<<NUM_CODES / 256, 256, 0, stream>>>(w, whi, wlo, t3);
    vq_main_kernel<<<NPTS / 64, 256, 0, stream>>>(z, w, whi, wlo, t3, out);
}

// Round 10
// 77.200 us; speedup vs baseline: 5.0900x; 1.2071x over previous
//
#include <hip/hip_runtime.h>
#include <math.h>

#define NUM_CODES 1024
#define DIM 64
#define HW 1024
#define NPTS 65536
#define CAP 16
#define W_WINDOW 6.0e-4f   // >= 2*Delta_hh (4.8e-4 worst-case); lambda~0.4

using short8 = __attribute__((ext_vector_type(8))) short;
using f32x4  = __attribute__((ext_vector_type(4))) float;

// ---- numpy-exact helpers (verified rounds 2-9: absmax 0.0) ----
__device__ __forceinline__ float pairwise_sumsq64(const float* v) {
    float r[8];
#pragma unroll
    for (int j = 0; j < 8; ++j) r[j] = __fmul_rn(v[j], v[j]);
#pragma unroll
    for (int i = 8; i < 64; i += 8) {
#pragma unroll
        for (int j = 0; j < 8; ++j)
            r[j] = __fadd_rn(r[j], __fmul_rn(v[i + j], v[i + j]));
    }
    return __fadd_rn(
        __fadd_rn(__fadd_rn(r[0], r[1]), __fadd_rn(r[2], r[3])),
        __fadd_rn(__fadd_rn(r[4], r[5]), __fadd_rn(r[6], r[7])));
}

__device__ __forceinline__ float replica_d(const float* x, const float* wr,
                                           float t1, float t3k) {
    float acc = 0.0f;
#pragma unroll
    for (int j = 0; j < 64; ++j) acc = __fmaf_rn(x[j], wr[j], acc);
    return __fadd_rn(__fsub_rn(t1, __fmul_rn(2.0f, acc)), t3k);
}

__device__ __forceinline__ unsigned short bf16_rne(float v) {
    unsigned int u = __float_as_uint(v);
    return (unsigned short)((u + 0x7fffu + ((u >> 16) & 1u)) >> 16);
}

// ---- Kernel 0: prep  w_hi (bf16) + t3 (numpy-exact) ----
__global__ void vq_prep_kernel(const float* __restrict__ w,
                               unsigned short* __restrict__ whi,
                               float* __restrict__ t3) {
    int k = blockIdx.x * blockDim.x + threadIdx.x;
    if (k >= NUM_CODES) return;
    float row[64];
#pragma unroll
    for (int j = 0; j < 64; ++j) row[j] = w[k * DIM + j];
    t3[k] = pairwise_sumsq64(row);
#pragma unroll
    for (int j = 0; j < 64; ++j) whi[k * DIM + j] = bf16_rne(row[j]);
}

// ---- Kernel 1: main. Block = 256 thr = 4 waves; 64 points (r4 skeleton).
// Code-split: wave wv handles ALL 4 point-tiles x codes [wv*256, wv*256+256).
__global__ __launch_bounds__(256, 2) void vq_main_kernel(
        const float* __restrict__ z,
        const float* __restrict__ w,
        const unsigned short* __restrict__ whi,
        const float* __restrict__ t3,
        float* __restrict__ out) {
    __shared__ __align__(16) unsigned short s_xhi[64 * 72];
    __shared__ float s_xf[64 * 66];
    __shared__ float s_pmin[4][64];
    __shared__ float s_thr[64];
    __shared__ int s_list[64 * CAP];
    __shared__ int s_cnt[64];
    __shared__ int s_best[64];

    const int tid = threadIdx.x;
    const int lane = tid & 63;
    const int wv = tid >> 6;          // 0..3
    const int n0 = blockIdx.x * 64;
    const int b = n0 >> 10;
    const int hw0 = n0 & (HW - 1);

    if (tid < 64) s_cnt[tid] = 0;

    // stage 64 points (f32 + bf16 hi) into LDS; coalesced global reads
    {
        int hw_off = tid & 63;
        int dbase = tid >> 6;
#pragma unroll
        for (int i = 0; i < 16; ++i) {
            int d = dbase + i * 4;
            float v = z[((size_t)(b * 64 + d)) * HW + hw0 + hw_off];
            s_xhi[hw_off * 72 + d] = bf16_rne(v);
            s_xf[hw_off * 66 + d] = v;
        }
    }
    __syncthreads();

    const int col = lane & 15;
    const int q = lane >> 4;

    // A fragments for all 4 point-tiles (hi only; layout verified r3-r9)
    short8 ah0[4], ah1[4];
#pragma unroll
    for (int at = 0; at < 4; ++at) {
        int arow = at * 16 + col;
        ah0[at] = *(const short8*)&s_xhi[arow * 72 + q * 8];
        ah1[at] = *(const short8*)&s_xhi[arow * 72 + 32 + q * 8];
    }

    const int T0 = wv * 16;

    // ---- pass 1: per-point min over this wave's 256 codes ----
    float s1[4][4];
#pragma unroll
    for (int at = 0; at < 4; ++at)
#pragma unroll
        for (int r = 0; r < 4; ++r) s1[at][r] = INFINITY;

#pragma unroll 4
    for (int t = 0; t < 16; ++t) {
        int code = (T0 + t) * 16 + col;
        short8 b0 = *(const short8*)(whi + code * 64 + q * 8);
        short8 b1 = *(const short8*)(whi + code * 64 + 32 + q * 8);
        float t3v = t3[code];
#pragma unroll
        for (int at = 0; at < 4; ++at) {
            f32x4 c = {0.f, 0.f, 0.f, 0.f};
            c = __builtin_amdgcn_mfma_f32_16x16x32_bf16(ah0[at], b0, c, 0, 0, 0);
            c = __builtin_amdgcn_mfma_f32_16x16x32_bf16(ah1[at], b1, c, 0, 0, 0);
#pragma unroll
            for (int r = 0; r < 4; ++r)
                s1[at][r] = fminf(s1[at][r], fmaf(-2.0f, c[r], t3v));
        }
    }

    // reduce over the 16 lanes (col bits) sharing each point
#pragma unroll
    for (int mask = 1; mask <= 8; mask <<= 1)
#pragma unroll
        for (int at = 0; at < 4; ++at)
#pragma unroll
            for (int r = 0; r < 4; ++r)
                s1[at][r] = fminf(s1[at][r], __shfl_xor(s1[at][r], mask, 64));

    if (col == 0) {
#pragma unroll
        for (int at = 0; at < 4; ++at)
#pragma unroll
            for (int r = 0; r < 4; ++r)
                s_pmin[wv][at * 16 + q * 4 + r] = s1[at][r];
    }
    __syncthreads();

    if (tid < 64) {
        float m = fminf(fminf(s_pmin[0][tid], s_pmin[1][tid]),
                        fminf(s_pmin[2][tid], s_pmin[3][tid]));
        s_thr[tid] = m + W_WINDOW;
    }
    __syncthreads();

    float thr[4][4];
#pragma unroll
    for (int at = 0; at < 4; ++at)
#pragma unroll
        for (int r = 0; r < 4; ++r)
            thr[at][r] = s_thr[at * 16 + q * 4 + r];

    // ---- pass 2: recompute scores (bitwise-identical), collect candidates ----
#pragma unroll 4
    for (int t = 0; t < 16; ++t) {
        int code = (T0 + t) * 16 + col;
        short8 b0 = *(const short8*)(whi + code * 64 + q * 8);
        short8 b1 = *(const short8*)(whi + code * 64 + 32 + q * 8);
        float t3v = t3[code];
#pragma unroll
        for (int at = 0; at < 4; ++at) {
            f32x4 c = {0.f, 0.f, 0.f, 0.f};
            c = __builtin_amdgcn_mfma_f32_16x16x32_bf16(ah0[at], b0, c, 0, 0, 0);
            c = __builtin_amdgcn_mfma_f32_16x16x32_bf16(ah1[at], b1, c, 0, 0, 0);
#pragma unroll
            for (int r = 0; r < 4; ++r) {
                float s = fmaf(-2.0f, c[r], t3v);
                if (s <= thr[at][r]) {
                    int pt = at * 16 + q * 4 + r;
                    int idx = atomicAdd(&s_cnt[pt], 1);
                    if (idx < CAP) s_list[pt * CAP + idx] = code;
                }
            }
        }
    }
    __syncthreads();

    // ---- selection: exact fp32 replica among candidates (x from LDS) ----
    if (tid < 64) {
        int pt = tid;
        int m = s_cnt[pt];
        const float* xrow = &s_xf[pt * 66];
        int best = s_list[pt * CAP];
        if (m > 1) {
            float t1 = pairwise_sumsq64(xrow);
            float dbest = INFINITY;
            if (m <= CAP) {
                int ks[CAP];
                for (int i = 0; i < m; ++i) ks[i] = s_list[pt * CAP + i];
                for (int i = 1; i < m; ++i) {          // sort ascending k
                    int key = ks[i]; int j2 = i - 1;
                    while (j2 >= 0 && ks[j2] > key) { ks[j2 + 1] = ks[j2]; --j2; }
                    ks[j2 + 1] = key;
                }
                for (int i = 0; i < m; ++i) {          // first-occurrence argmin
                    int k = ks[i];
                    float d = replica_d(xrow, w + (size_t)k * DIM, t1, t3[k]);
                    if (d < dbest) { dbest = d; best = k; }
                }
            } else {
                // overflow guard (P ~ 1e-15): 4-way-ILP exact scan, ascending k
                best = 0;
                for (int k = 0; k < NUM_CODES; k += 4) {
                    float a0 = 0.f, a1 = 0.f, a2 = 0.f, a3 = 0.f;
#pragma unroll
                    for (int j = 0; j < 64; ++j) {
                        float xv = xrow[j];
                        a0 = __fmaf_rn(xv, w[(size_t)(k + 0) * DIM + j], a0);
                        a1 = __fmaf_rn(xv, w[(size_t)(k + 1) * DIM + j], a1);
                        a2 = __fmaf_rn(xv, w[(size_t)(k + 2) * DIM + j], a2);
                        a3 = __fmaf_rn(xv, w[(size_t)(k + 3) * DIM + j], a3);
                    }
                    float dd[4];
                    dd[0] = __fadd_rn(__fsub_rn(t1, __fmul_rn(2.0f, a0)), t3[k + 0]);
                    dd[1] = __fadd_rn(__fsub_rn(t1, __fmul_rn(2.0f, a1)), t3[k + 1]);
                    dd[2] = __fadd_rn(__fsub_rn(t1, __fmul_rn(2.0f, a2)), t3[k + 2]);
                    dd[3] = __fadd_rn(__fsub_rn(t1, __fmul_rn(2.0f, a3)), t3[k + 3]);
#pragma unroll
                    for (int u = 0; u < 4; ++u)
                        if (dd[u] < dbest) { dbest = dd[u]; best = k + u; }
                }
            }
        }
        s_best[pt] = best;
    }
    __syncthreads();

    // ---- output: out[b, c, hw0+pt] = w[best[pt]][c], coalesced 64-wide ----
    {
        int pt = tid & 63;
        int cb = tid >> 6;            // 0..3
        int bk = s_best[pt];
        const float* wrow = w + (size_t)bk * DIM;
#pragma unroll
        for (int i = 0; i < 16; ++i) {
            int c = cb + i * 4;
            out[((size_t)(b * 64 + c)) * HW + hw0 + pt] = wrow[c];
        }
    }
}

extern "C" void kernel_launch(void* const* d_in, const int* in_sizes, int n_in,
                              void* d_out, int out_size, void* d_ws, size_t ws_size,
                              hipStream_t stream) {
    const float* z = (const float*)d_in[0];
    const float* w = (const float*)d_in[1];
    float* out = (float*)d_out;

    unsigned short* whi = (unsigned short*)d_ws;        // 128 KB
    float* t3 = (float*)((char*)d_ws + 131072);         // 4 KB

    vq_prep_kernel<<<NUM_CODES / 256, 256, 0, stream>>>(w, whi, t3);
    vq_main_kernel<<<NPTS / 64, 256, 0, stream>>>(z, w, whi, t3, out);
}